// Round 1
// baseline (25.759 us; speedup 1.0000x reference)
//
#include <hip/hip_runtime.h>

// GraphSAGE encoder forward, fused single kernel.
// Inputs (setup_inputs order):
//  d_in[0] emb       f32 [1M, 128]
//  d_in[1] neigh_w   f32 [8192, 10]
//  d_in[2] W         f32 [256, 128]
//  d_in[3] b         f32 [128]
//  d_in[4] nodes     i32 [8192]
//  d_in[5] neigh_ids i32 [8192, 10]
// Output: f32 [8192, 128]  = swish(concat(self, weighted-mean-neigh) @ W + b)

#define B_NODES 8192
#define K_NEIGH 10
#define FDIM 128
#define EDIM 128
#define NPB 16           // nodes per block
#define THREADS 256

__global__ __launch_bounds__(THREADS) void sage_fused(
    const float* __restrict__ emb,
    const float* __restrict__ neigh_w,
    const float* __restrict__ Wm,
    const float* __restrict__ bias,
    const int*   __restrict__ nodes,
    const int*   __restrict__ neigh_ids,
    float* __restrict__ out)
{
    __shared__ __align__(16) float Xs[NPB][2 * FDIM];   // 16 x 256 f32 = 16 KB

    const int tid  = threadIdx.x;
    const int lane = tid & 63;
    const int wave = tid >> 6;          // 0..3
    const int nb0  = blockIdx.x * NPB;

    // ---------------- Phase 1: gather + weighted aggregate into LDS ----------
    // Each wave handles NPB/4 = 4 nodes; each lane covers 2 feature dims (float2).
    const int d0 = lane * 2;
    #pragma unroll
    for (int i = 0; i < NPB / 4; ++i) {
        const int nl = wave * (NPB / 4) + i;
        const int nb = nb0 + nl;

        // self features
        const int sid = nodes[nb];
        const float2 sv = *reinterpret_cast<const float2*>(&emb[sid * FDIM + d0]);

        // raw weights + row sum (wave-uniform addresses -> broadcast loads)
        float wk[K_NEIGH];
        float wsum = 0.f;
        #pragma unroll
        for (int k = 0; k < K_NEIGH; ++k) {
            wk[k] = neigh_w[nb * K_NEIGH + k];
            wsum += wk[k];
        }
        const float inv = 1.f / wsum;

        // weighted neighbor mean
        float ax = 0.f, ay = 0.f;
        #pragma unroll
        for (int k = 0; k < K_NEIGH; ++k) {
            const int id = neigh_ids[nb * K_NEIGH + k];
            const float2 v = *reinterpret_cast<const float2*>(&emb[id * FDIM + d0]);
            ax = fmaf(wk[k], v.x, ax);
            ay = fmaf(wk[k], v.y, ay);
        }

        Xs[nl][d0]            = sv.x;
        Xs[nl][d0 + 1]        = sv.y;
        Xs[nl][FDIM + d0]     = ax * inv;
        Xs[nl][FDIM + d0 + 1] = ay * inv;
    }
    __syncthreads();

    // ---------------- Phase 2: [NPB x 256] @ W[256 x 128] + b, swish ---------
    // thread -> output column e = tid & 127; node group g = tid >> 7 (0..1),
    // each thread computes NPB/2 = 8 output rows for its column.
    const int e = tid & (EDIM - 1);
    const int g = tid >> 7;

    float acc[NPB / 2];
    const float bv = bias[e];
    #pragma unroll
    for (int i = 0; i < NPB / 2; ++i) acc[i] = bv;

    for (int d = 0; d < 2 * FDIM; d += 4) {
        // W column reads: coalesced across e (consecutive lanes, consecutive addrs),
        // waves 2/3 repeat waves 0/1 addresses -> L1 hits.
        const float w0 = Wm[(d + 0) * EDIM + e];
        const float w1 = Wm[(d + 1) * EDIM + e];
        const float w2 = Wm[(d + 2) * EDIM + e];
        const float w3 = Wm[(d + 3) * EDIM + e];
        #pragma unroll
        for (int i = 0; i < NPB / 2; ++i) {
            // broadcast ds_read_b128: every lane in the wave reads the same addr
            const float4 xv = *reinterpret_cast<const float4*>(&Xs[g * (NPB / 2) + i][d]);
            acc[i] = fmaf(xv.x, w0, fmaf(xv.y, w1, fmaf(xv.z, w2, fmaf(xv.w, w3, acc[i]))));
        }
    }

    #pragma unroll
    for (int i = 0; i < NPB / 2; ++i) {
        const int row = nb0 + g * (NPB / 2) + i;
        const float h = acc[i];
        out[row * EDIM + e] = h / (1.f + __expf(-h));   // h * sigmoid(h)
    }
}

extern "C" void kernel_launch(void* const* d_in, const int* in_sizes, int n_in,
                              void* d_out, int out_size, void* d_ws, size_t ws_size,
                              hipStream_t stream) {
    const float* emb       = (const float*)d_in[0];
    const float* neigh_w   = (const float*)d_in[1];
    const float* Wm        = (const float*)d_in[2];
    const float* bias      = (const float*)d_in[3];
    const int*   nodes     = (const int*)d_in[4];
    const int*   neigh_ids = (const int*)d_in[5];
    float* out = (float*)d_out;

    const int blocks = B_NODES / NPB;   // 512
    sage_fused<<<dim3(blocks), dim3(THREADS), 0, stream>>>(
        emb, neigh_w, Wm, bias, nodes, neigh_ids, out);
}